// Round 17
// baseline (101.802 us; speedup 1.0000x reference)
//
#include <hip/hip_runtime.h>

#define NAGENTS 32
#define NOBSV   2
#define H1D     128
#define HXD     64
#define NACTD   5

typedef _Float16 h8 __attribute__((ext_vector_type(8)));
typedef float f32x4 __attribute__((ext_vector_type(4)));

// MFMA 16x16x32 f16 layouts (validated rounds 8-16):
//   A: lane l holds A[l&15][(l>>4)*8 + j]
//   B: lane l holds B[(l>>4)*8 + j][l&15]
//   D: reg r holds D[(l>>4)*4 + r][l&15]
// Symmetry: A-frag image of M^T == B-frag image of M -> wfrag serves both roles.
// ci buffer: [agent][row][128] f16 — cols 0..63 = hidden (K1), 64..127 = comms (K2).
// wfrag: [mat*32 + a][1024] h8 — single-f16 fragment images (1 MB, L2-resident).
// Mask math: f32 with margin screen (1e-4 >> 2e-6 f32 error bound) + exact-f64
// fallback for borderline pairs -> verdicts bit-identical to numpy-f64 reference.

static __device__ __forceinline__ float fast_tanh(float x) {
    float e = __builtin_amdgcn_exp2f(x * 2.885390081777927f);  // exp(2x)
    return fmaf(-2.0f, __builtin_amdgcn_rcpf(e + 1.0f), 1.0f);
}

// ================= Kernel 0: weight fragment prep (per agent, once) =================
__global__ __launch_bounds__(256, 4) void k0_prep(
    const float* __restrict__ W2, const float* __restrict__ Wc,
    h8* __restrict__ wfrag)
{
    const int a = blockIdx.x;
    const int tid = threadIdx.x;
    #pragma unroll
    for (int mat = 0; mat < 2; ++mat) {
        const float* src = (mat == 0 ? W2 : Wc) + (size_t)a * (H1D * HXD);
        h8* dst = wfrag + (size_t)(mat * NAGENTS + a) * 1024;
        #pragma unroll
        for (int s4 = 0; s4 < 4; ++s4) {
            const int s  = tid + s4 * 256;
            const int fi = s >> 6, ln = s & 63;
            const int k0  = (fi >> 2) * 32 + (ln >> 4) * 8;
            const int col = (fi & 3) * 16 + (ln & 15);
            h8 w;
            #pragma unroll
            for (int j = 0; j < 8; ++j)
                w[j] = (_Float16)src[(size_t)(k0 + j) * HXD + col];
            dst[s] = w;
        }
    }
}

// ============================ Kernel 1: encoder ============================
// grid (NAGENTS, B/128). B-frags staged wfrag->LDS (coalesced); ci writes contiguous.
__global__ __launch_bounds__(256, 4) void k1_encoder(
    const float* __restrict__ obs, const float* __restrict__ W1,
    const float* __restrict__ b1, const float* __restrict__ b2,
    _Float16* __restrict__ ci, const h8* __restrict__ wfrag, int B)
{
    __shared__ h8    s_wf[16][64];
    __shared__ float s_w1a[H1D], s_w1b[H1D], s_b1[H1D], s_b2[HXD];
    __shared__ float s_ob[128][2];

    const int a   = blockIdx.x;
    const int r0  = blockIdx.y * 128;
    const int tid = threadIdx.x;
    const int wv  = tid >> 6, lane = tid & 63;
    const int l15 = lane & 15, lq = lane >> 4;

    {
        const float* w1p = W1 + a * (NOBSV * H1D);
        if (tid < H1D) {
            s_w1a[tid] = w1p[tid];
            s_w1b[tid] = w1p[H1D + tid];
            s_b1[tid]  = b1[a * H1D + tid];
        } else if (tid < H1D + HXD) {
            s_b2[tid - H1D] = b2[a * HXD + (tid - H1D)];
        }
        if (tid < 128) {
            const float2 ov = *reinterpret_cast<const float2*>(
                obs + ((size_t)(r0 + tid) * NAGENTS + a) * NOBSV);
            s_ob[tid][0] = ov.x; s_ob[tid][1] = ov.y;
        }
        const h8* srcf = wfrag + (size_t)a * 1024;
        h8* dstf = &s_wf[0][0];
        #pragma unroll
        for (int c = 0; c < 4; ++c) dstf[tid + c * 256] = srcf[tid + c * 256];
    }
    __syncthreads();

    const float o0r0 = s_ob[wv * 32 + l15][0],      o1r0 = s_ob[wv * 32 + l15][1];
    const float o0r1 = s_ob[wv * 32 + 16 + l15][0], o1r1 = s_ob[wv * 32 + 16 + l15][1];

    f32x4 acc[2][4];
    #pragma unroll
    for (int m = 0; m < 2; ++m)
        #pragma unroll
        for (int n = 0; n < 4; ++n) {
            const float bv = s_b2[n * 16 + l15];
            acc[m][n] = (f32x4){bv, bv, bv, bv};
        }
    #pragma unroll
    for (int kt = 0; kt < 4; ++kt) {
        h8 af0, af1;
        #pragma unroll
        for (int j = 0; j < 8; ++j) {
            const int k = kt * 32 + lq * 8 + j;
            const float wa = s_w1a[k], wb = s_w1b[k], bb = s_b1[k];
            af0[j] = (_Float16)fmaxf(fmaf(o1r0, wb, fmaf(o0r0, wa, bb)), 0.0f);
            af1[j] = (_Float16)fmaxf(fmaf(o1r1, wb, fmaf(o0r1, wa, bb)), 0.0f);
        }
        #pragma unroll
        for (int n = 0; n < 4; ++n) {
            h8 bh = s_wf[kt * 4 + n][lane];
            acc[0][n] = __builtin_amdgcn_mfma_f32_16x16x32_f16(af0, bh, acc[0][n], 0, 0, 0);
            acc[1][n] = __builtin_amdgcn_mfma_f32_16x16x32_f16(af1, bh, acc[1][n], 0, 0, 0);
        }
    }
    #pragma unroll
    for (int m = 0; m < 2; ++m)
        #pragma unroll
        for (int r = 0; r < 4; ++r) {
            const int row = wv * 32 + m * 16 + lq * 4 + r;
            _Float16* dst = ci + ((size_t)a * B + (r0 + row)) * 128;
            #pragma unroll
            for (int n = 0; n < 4; ++n)
                dst[n * 16 + l15] = (_Float16)fmaxf(acc[m][n][r], 0.0f);
        }
}

// ========================= Kernel 2: mask + comms (MFMA) =========================
// grid (B/8). Wave w owns rows 2w,2w+1. Mask: f32 screen + exact-f64 fallback
// (bit-identical to numpy-f64). LDS ~43.6 KB -> 3 blocks/CU.
__global__ __launch_bounds__(256, 3) void k2_comms(
    const float* __restrict__ obs, _Float16* __restrict__ ci, int B)
{
    __shared__ __align__(16) _Float16 s_tt[8][64][40];  // hidden transposed [o][j]
    __shared__ float s_o[8][66];
    __shared__ float s_Ji[8][32];

    const int r0  = blockIdx.x * 8;
    const int tid = threadIdx.x;
    const int wv  = tid >> 6, lane = tid & 63;
    const int l15 = lane & 15, lq = lane >> 4;

    if (tid < 128) {
        const float4 v = reinterpret_cast<const float4*>(obs + (size_t)r0 * NAGENTS * NOBSV)[tid];
        const int row = tid >> 4, seg = tid & 15;
        *reinterpret_cast<float4*>(&s_o[row][seg * 4]) = v;
    }
    __syncthreads();

    const int row = tid >> 5;   // block-local row; wave wv holds rows 2wv, 2wv+1
    const int u   = tid & 31;

    {   // transposed hidden (ci cols 0..63), agent-major layout
        const h8* src = reinterpret_cast<const h8*>(
            ci + ((size_t)u * B + (r0 + row)) * 128);
        #pragma unroll
        for (int c = 0; c < 8; ++c) {
            h8 v = src[c];
            #pragma unroll
            for (int e = 0; e < 8; ++e) s_tt[row][c * 8 + e][u] = v[e];
        }
    }
    unsigned int bits = 0u;
    {   // mask row: f32 with margin screen; rare borderline pairs recomputed in
        // exact f64 (all intermediates <=27 bits -> f64 is the true value).
        // f32 chain abs error <= ~2e-6 << 1e-4 margin -> verdicts bit-exact.
        const float xif = s_o[row][u * 2 + 0] * 2.0f;
        const float yif = s_o[row][u * 2 + 1] * 6.0f;
        #pragma unroll 4
        for (int j = 0; j < NAGENTS; ++j) {
            const float xj = s_o[row][j * 2 + 0] * 2.0f;
            const float yj = s_o[row][j * 2 + 1] * 6.0f;
            const float d = fabsf(xif - xj) + fabsf(yif - yj);
            bool in;
            if (__builtin_expect(d > 1e-4f && fabsf(d - 2.0f) > 1e-4f, 1)) {
                in = (d < 2.0f);
            } else {
                const double xi64 = (double)s_o[row][u * 2 + 0] * 2.0;
                const double yi64 = (double)s_o[row][u * 2 + 1] * 6.0;
                const double xj64 = (double)s_o[row][j * 2 + 0] * 2.0;
                const double yj64 = (double)s_o[row][j * 2 + 1] * 6.0;
                const double dd = fabs(xi64 - xj64) + fabs(yi64 - yj64);
                in = (dd > 0.0 && dd < 2.0);
            }
            if (in) bits |= (1u << j);
        }
        s_Ji[row][u] = 1.0f / fmaxf((float)__popc(bits), 1.0f);
    }
    asm volatile("s_waitcnt lgkmcnt(0)" ::: "memory");
    __builtin_amdgcn_sched_barrier(0);

    #pragma unroll
    for (int rr = 0; rr < 2; ++rr) {
        const int rw = wv * 2 + rr;
        const unsigned int ba0 = (unsigned int)__shfl((int)bits, rr * 32 + l15, 64);
        const unsigned int ba1 = (unsigned int)__shfl((int)bits, rr * 32 + 16 + l15, 64);
        h8 a0, a1;
        #pragma unroll
        for (int j = 0; j < 8; ++j) {
            a0[j] = ((ba0 >> (lq * 8 + j)) & 1u) ? (_Float16)1.0f : (_Float16)0.0f;
            a1[j] = ((ba1 >> (lq * 8 + j)) & 1u) ? (_Float16)1.0f : (_Float16)0.0f;
        }
        f32x4 acc[2][4];
        #pragma unroll
        for (int m = 0; m < 2; ++m)
            #pragma unroll
            for (int n = 0; n < 4; ++n) acc[m][n] = (f32x4){0.f, 0.f, 0.f, 0.f};
        #pragma unroll
        for (int n = 0; n < 4; ++n) {
            h8 b = *reinterpret_cast<const h8*>(&s_tt[rw][n * 16 + l15][lq * 8]);
            acc[0][n] = __builtin_amdgcn_mfma_f32_16x16x32_f16(a0, b, acc[0][n], 0, 0, 0);
            acc[1][n] = __builtin_amdgcn_mfma_f32_16x16x32_f16(a1, b, acc[1][n], 0, 0, 0);
        }
        #pragma unroll
        for (int m = 0; m < 2; ++m)
            #pragma unroll
            for (int r = 0; r < 4; ++r) {
                const int ai = m * 16 + lq * 4 + r;
                const float Ji = s_Ji[rw][ai];
                _Float16* dst = ci + ((size_t)ai * B + (r0 + rw)) * 128 + 64;
                #pragma unroll
                for (int n = 0; n < 4; ++n)
                    dst[n * 16 + l15] = (_Float16)(acc[m][n][r] * Ji);
            }
    }
}

// ==================== Kernel 3: comm MLP + decoder (MFMA, swapped operands) ====================
// grid (NAGENTS, B/128). D = Wc^T @ ci -> D[o][row]: A = wfrag, B = ci rows.
// Epilogue: decoder dot lane-local over 16 o-dims; reduce = 2 shfl rounds.
__global__ __launch_bounds__(256, 4) void k3_head(
    const _Float16* __restrict__ ci, const float* __restrict__ bc,
    const float* __restrict__ Wd, const float* __restrict__ bd,
    float* __restrict__ out, const h8* __restrict__ wfrag, int B)
{
    __shared__ h8    s_wf[16][64];
    __shared__ float s_wd[HXD][9];   // stride 9 -> conflict-free
    __shared__ float s_bc[HXD];
    __shared__ float s_bd[8];

    const int a   = blockIdx.x;
    const int r0  = blockIdx.y * 128;
    const int tid = threadIdx.x;
    const int wv  = tid >> 6, lane = tid & 63;
    const int l15 = lane & 15, lq = lane >> 4;

    {
        const h8* srcf = wfrag + (size_t)(NAGENTS + a) * 1024;
        h8* dstf = &s_wf[0][0];
        #pragma unroll
        for (int c = 0; c < 4; ++c) dstf[tid + c * 256] = srcf[tid + c * 256];
        if (tid < HXD) {
            s_bc[tid] = bc[a * HXD + tid];
            #pragma unroll
            for (int o = 0; o < NACTD; ++o)
                s_wd[tid][o] = Wd[(size_t)a * (HXD * NACTD) + tid * NACTD + o];
        } else if (tid < HXD + NACTD) {
            s_bd[tid - HXD] = bd[a * NACTD + (tid - HXD)];
        }
    }
    __syncthreads();

    // B-fragments: lane l holds ci[row = base + l15][k = kt*32 + lq*8 + j]
    const _Float16* rb0 = ci + ((size_t)a * B + (r0 + wv * 32 + l15)) * 128;
    const _Float16* rb1 = rb0 + (size_t)16 * 128;

    // acc[m][n]: o-tile m (o = m*16 + lq*4 + r), row-tile n (row = wv*32 + n*16 + l15)
    f32x4 acc[4][2];
    #pragma unroll
    for (int m = 0; m < 4; ++m) {
        const float4 bv = *reinterpret_cast<const float4*>(&s_bc[m * 16 + lq * 4]);
        acc[m][0] = (f32x4){bv.x, bv.y, bv.z, bv.w};
        acc[m][1] = (f32x4){bv.x, bv.y, bv.z, bv.w};
    }
    #pragma unroll
    for (int kt = 0; kt < 4; ++kt) {
        h8 bf0 = *reinterpret_cast<const h8*>(rb0 + kt * 32 + lq * 8);
        h8 bf1 = *reinterpret_cast<const h8*>(rb1 + kt * 32 + lq * 8);
        #pragma unroll
        for (int m = 0; m < 4; ++m) {
            h8 ah = s_wf[kt * 4 + m][lane];
            acc[m][0] = __builtin_amdgcn_mfma_f32_16x16x32_f16(ah, bf0, acc[m][0], 0, 0, 0);
            acc[m][1] = __builtin_amdgcn_mfma_f32_16x16x32_f16(ah, bf1, acc[m][1], 0, 0, 0);
        }
    }

    // epilogue: tanh + decoder (lane-local 16 o-dims) + 2-round reduce + store
    #pragma unroll
    for (int n = 0; n < 2; ++n) {
        float qv[NACTD];
        #pragma unroll
        for (int o = 0; o < NACTD; ++o) qv[o] = 0.0f;
        #pragma unroll
        for (int m = 0; m < 4; ++m)
            #pragma unroll
            for (int r = 0; r < 4; ++r) {
                const float t = fast_tanh(acc[m][n][r]);
                const float* wd = s_wd[m * 16 + lq * 4 + r];
                #pragma unroll
                for (int o = 0; o < NACTD; ++o) qv[o] = fmaf(t, wd[o], qv[o]);
            }
        #pragma unroll
        for (int o = 0; o < NACTD; ++o) {
            qv[o] += __shfl_xor(qv[o], 16, 64);
            qv[o] += __shfl_xor(qv[o], 32, 64);
        }
        if (lq == 0) {
            const int row = wv * 32 + n * 16 + l15;
            float* op = out + ((size_t)(r0 + row) * NAGENTS + a) * NACTD;
            #pragma unroll
            for (int o = 0; o < NACTD; ++o) op[o] = qv[o] + s_bd[o];
        }
    }
}

// ================= Fallback: round-6 fused kernel (passed @991us) =================
#define TBATCH  8
#define NWAVES  4
#define BFST    2056
#define HROWST  132
__global__ __launch_bounds__(256, 3) void qnet_fused_fb(
    const float* __restrict__ obs,
    const float* __restrict__ W1, const float* __restrict__ b1,
    const float* __restrict__ W2, const float* __restrict__ b2,
    const float* __restrict__ Wc, const float* __restrict__ bc,
    const float* __restrict__ Wd, const float* __restrict__ bd,
    float* __restrict__ out)
{
    __shared__ float    s_obs[TBATCH][NAGENTS * 2 + 2];
    __shared__ _Float16 s_hid[TBATCH * BFST];
    __shared__ float    s_h[NWAVES][TBATCH][HROWST];

    const int tid  = threadIdx.x;
    const int wave = tid >> 6;
    const int lane = tid & 63;
    const int lb   = lane & 7;
    const int og   = lane >> 3;
    const int b0   = blockIdx.x * TBATCH;

    {
        const float2* src = reinterpret_cast<const float2*>(obs + (size_t)b0 * (NAGENTS * NOBSV));
        float2 v = src[tid];
        s_obs[tid >> 5][(tid & 31) * 2 + 0] = v.x;
        s_obs[tid >> 5][(tid & 31) * 2 + 1] = v.y;
    }
    __syncthreads();

    const int p_a = tid >> 3;
    const int p_b = tid & 7;
    unsigned int bits = 0u;
    float Jf;
    {
        const double xi = (double)s_obs[p_b][p_a * 2 + 0] * 2.0;
        const double yi = (double)s_obs[p_b][p_a * 2 + 1] * 6.0;
        #pragma unroll
        for (int j = 0; j < NAGENTS; ++j) {
            double xj = (double)s_obs[p_b][j * 2 + 0] * 2.0;
            double yj = (double)s_obs[p_b][j * 2 + 1] * 6.0;
            double d = fabs(xi - xj) + fabs(yi - yj);
            if (d > 0.0 && d < 2.0) bits |= (1u << j);
        }
        Jf = fmaxf((float)__popc(bits), 1.0f);
    }

    #pragma unroll 1
    for (int ai = 0; ai < 8; ++ai) {
        const int a = wave * 8 + ai;
        const float o0 = s_obs[lb][a * 2 + 0];
        const float o1 = s_obs[lb][a * 2 + 1];
        {
            const float* __restrict__ w1a = W1 + a * (NOBSV * H1D) + og * 16;
            const float* __restrict__ w1b = w1a + H1D;
            const float* __restrict__ b1p = b1 + a * H1D + og * 16;
            float* hdst = &s_h[wave][lb][og * 16];
            #pragma unroll
            for (int c = 0; c < 4; ++c) {
                float4 wa = *reinterpret_cast<const float4*>(w1a + 4 * c);
                float4 wb = *reinterpret_cast<const float4*>(w1b + 4 * c);
                float4 bv = *reinterpret_cast<const float4*>(b1p + 4 * c);
                float4 hv;
                hv.x = fmaxf(fmaf(o1, wb.x, fmaf(o0, wa.x, bv.x)), 0.0f);
                hv.y = fmaxf(fmaf(o1, wb.y, fmaf(o0, wa.y, bv.y)), 0.0f);
                hv.z = fmaxf(fmaf(o1, wb.z, fmaf(o0, wa.z, bv.z)), 0.0f);
                hv.w = fmaxf(fmaf(o1, wb.w, fmaf(o0, wa.w, bv.w)), 0.0f);
                *reinterpret_cast<float4*>(hdst + 4 * c) = hv;
            }
        }
        asm volatile("s_waitcnt lgkmcnt(0)" ::: "memory");
        __builtin_amdgcn_sched_barrier(0);

        const float* __restrict__ w2p = W2 + a * (H1D * HXD) + og * 8;
        const float* __restrict__ b2p = b2 + a * HXD + og * 8;
        float acc[8];
        {
            float4 bv0 = *reinterpret_cast<const float4*>(b2p + 0);
            float4 bv1 = *reinterpret_cast<const float4*>(b2p + 4);
            acc[0] = bv0.x; acc[1] = bv0.y; acc[2] = bv0.z; acc[3] = bv0.w;
            acc[4] = bv1.x; acc[5] = bv1.y; acc[6] = bv1.z; acc[7] = bv1.w;
        }
        const float* hsrc = &s_h[wave][lb][0];
        #pragma unroll 8
        for (int k = 0; k < H1D; ++k) {
            const float hv = hsrc[k];
            const float* wr = w2p + k * HXD;
            float4 wv0 = *reinterpret_cast<const float4*>(wr + 0);
            float4 wv1 = *reinterpret_cast<const float4*>(wr + 4);
            acc[0] = fmaf(hv, wv0.x, acc[0]);
            acc[1] = fmaf(hv, wv0.y, acc[1]);
            acc[2] = fmaf(hv, wv0.z, acc[2]);
            acc[3] = fmaf(hv, wv0.w, acc[3]);
            acc[4] = fmaf(hv, wv1.x, acc[4]);
            acc[5] = fmaf(hv, wv1.y, acc[5]);
            acc[6] = fmaf(hv, wv1.z, acc[6]);
            acc[7] = fmaf(hv, wv1.w, acc[7]);
        }
        h8 hh;
        #pragma unroll
        for (int i = 0; i < 8; ++i) hh[i] = (_Float16)fmaxf(acc[i], 0.0f);
        *reinterpret_cast<h8*>(&s_hid[lb * BFST + a * HXD + og * 8]) = hh;
    }
    __syncthreads();

    #pragma unroll 1
    for (int ai = 0; ai < 8; ++ai) {
        const int a = wave * 8 + ai;
        const int srcm = ai * 8 + lb;
        const unsigned int mbits = (unsigned int)__shfl((int)bits, srcm, 64);
        const float Jv = __shfl(Jf, srcm, 64);

        float cm8[8];
        #pragma unroll
        for (int i = 0; i < 8; ++i) cm8[i] = 0.0f;
        {
            const _Float16* hrow = &s_hid[lb * BFST + og * 8];
            #pragma unroll 8
            for (int j = 0; j < NAGENTS; ++j) {
                const float m = (float)((mbits >> j) & 1u);
                h8 v = *reinterpret_cast<const h8*>(hrow + j * HXD);
                cm8[0] = fmaf(m, (float)v[0], cm8[0]);
                cm8[1] = fmaf(m, (float)v[1], cm8[1]);
                cm8[2] = fmaf(m, (float)v[2], cm8[2]);
                cm8[3] = fmaf(m, (float)v[3], cm8[3]);
                cm8[4] = fmaf(m, (float)v[4], cm8[4]);
                cm8[5] = fmaf(m, (float)v[5], cm8[5]);
                cm8[6] = fmaf(m, (float)v[6], cm8[6]);
                cm8[7] = fmaf(m, (float)v[7], cm8[7]);
            }
        }
        {
            float* cw = &s_h[wave][lb][og * 8];
            *reinterpret_cast<float4*>(cw + 0) =
                make_float4(cm8[0]/Jv, cm8[1]/Jv, cm8[2]/Jv, cm8[3]/Jv);
            *reinterpret_cast<float4*>(cw + 4) =
                make_float4(cm8[4]/Jv, cm8[5]/Jv, cm8[6]/Jv, cm8[7]/Jv);
        }
        asm volatile("s_waitcnt lgkmcnt(0)" ::: "memory");
        __builtin_amdgcn_sched_barrier(0);

        const float* __restrict__ wcp = Wc + a * (2 * HXD * HXD) + og * 8;
        const float* __restrict__ bcp = bc + a * HXD + og * 8;
        float acc[8];
        {
            float4 bv0 = *reinterpret_cast<const float4*>(bcp + 0);
            float4 bv1 = *reinterpret_cast<const float4*>(bcp + 4);
            acc[0] = bv0.x; acc[1] = bv0.y; acc[2] = bv0.z; acc[3] = bv0.w;
            acc[4] = bv1.x; acc[5] = bv1.y; acc[6] = bv1.z; acc[7] = bv1.w;
        }
        const _Float16* hbase = &s_hid[lb * BFST + a * HXD];
        #pragma unroll 8
        for (int k = 0; k < HXD; ++k) {
            const float ci2 = (float)hbase[k];
            const float* wr = wcp + k * HXD;
            float4 wv0 = *reinterpret_cast<const float4*>(wr + 0);
            float4 wv1 = *reinterpret_cast<const float4*>(wr + 4);
            acc[0] = fmaf(ci2, wv0.x, acc[0]);
            acc[1] = fmaf(ci2, wv0.y, acc[1]);
            acc[2] = fmaf(ci2, wv0.z, acc[2]);
            acc[3] = fmaf(ci2, wv0.w, acc[3]);
            acc[4] = fmaf(ci2, wv1.x, acc[4]);
            acc[5] = fmaf(ci2, wv1.y, acc[5]);
            acc[6] = fmaf(ci2, wv1.z, acc[6]);
            acc[7] = fmaf(ci2, wv1.w, acc[7]);
        }
        #pragma unroll 8
        for (int k2 = 0; k2 < HXD; ++k2) {
            const float ci2 = s_h[wave][lb][k2];
            const float* wr = wcp + (HXD + k2) * HXD;
            float4 wv0 = *reinterpret_cast<const float4*>(wr + 0);
            float4 wv1 = *reinterpret_cast<const float4*>(wr + 4);
            acc[0] = fmaf(ci2, wv0.x, acc[0]);
            acc[1] = fmaf(ci2, wv0.y, acc[1]);
            acc[2] = fmaf(ci2, wv0.z, acc[2]);
            acc[3] = fmaf(ci2, wv0.w, acc[3]);
            acc[4] = fmaf(ci2, wv1.x, acc[4]);
            acc[5] = fmaf(ci2, wv1.y, acc[5]);
            acc[6] = fmaf(ci2, wv1.z, acc[6]);
            acc[7] = fmaf(ci2, wv1.w, acc[7]);
        }
        float qv[NACTD];
        #pragma unroll
        for (int o = 0; o < NACTD; ++o) qv[o] = 0.0f;
        const float* __restrict__ wdp = Wd + a * (HXD * NACTD) + og * 8 * NACTD;
        #pragma unroll
        for (int i = 0; i < 8; ++i) {
            float h2 = tanhf(acc[i]);
            #pragma unroll
            for (int o = 0; o < NACTD; ++o)
                qv[o] = fmaf(h2, wdp[i * NACTD + o], qv[o]);
        }
        #pragma unroll
        for (int o = 0; o < NACTD; ++o) {
            qv[o] += __shfl_xor(qv[o], 8, 64);
            qv[o] += __shfl_xor(qv[o], 16, 64);
            qv[o] += __shfl_xor(qv[o], 32, 64);
        }
        if (og == 0) {
            float* op = out + ((size_t)(b0 + lb) * NAGENTS + a) * NACTD;
            const float* bdp = bd + a * NACTD;
            #pragma unroll
            for (int o = 0; o < NACTD; ++o) op[o] = qv[o] + bdp[o];
        }
    }
}

extern "C" void kernel_launch(void* const* d_in, const int* in_sizes, int n_in,
                              void* d_out, int out_size, void* d_ws, size_t ws_size,
                              hipStream_t stream) {
    (void)out_size;
    if (n_in < 9) return;
    const float* obs = (const float*)d_in[0];
    const float* W1  = (const float*)d_in[1];
    const float* b1v = (const float*)d_in[2];
    const float* W2  = (const float*)d_in[3];
    const float* b2v = (const float*)d_in[4];
    const float* Wc  = (const float*)d_in[5];
    const float* bcv = (const float*)d_in[6];
    const float* Wd  = (const float*)d_in[7];
    const float* bdv = (const float*)d_in[8];
    float* out = (float*)d_out;
    const int Btot = in_sizes[0] / (NAGENTS * NOBSV);  // 16384

    const size_t ciBytes   = (size_t)Btot * NAGENTS * 128 * 2;  // 134 MB
    const size_t fragBytes = (size_t)2 * NAGENTS * 1024 * 16;   // 1 MB
    dim3 blk(256);
    if (ws_size >= ciBytes + fragBytes && (Btot % 128) == 0) {
        _Float16* ci = (_Float16*)d_ws;
        h8* wfrag = (h8*)((char*)d_ws + ciBytes);
        k0_prep<<<dim3(NAGENTS), blk, 0, stream>>>(W2, Wc, wfrag);
        k1_encoder<<<dim3(NAGENTS, Btot / 128), blk, 0, stream>>>(
            obs, W1, b1v, b2v, ci, wfrag, Btot);
        k2_comms<<<dim3(Btot / 8), blk, 0, stream>>>(obs, ci, Btot);
        k3_head<<<dim3(NAGENTS, Btot / 128), blk, 0, stream>>>(
            ci, bcv, Wd, bdv, out, wfrag, Btot);
    } else {
        qnet_fused_fb<<<dim3(Btot / TBATCH), dim3(256), 0, stream>>>(
            obs, W1, b1v, W2, b2v, Wc, bcv, Wd, bdv, out);
    }
}

// Round 18
// 98.418 us; speedup vs baseline: 1.0344x; 1.0344x over previous
//
#include <hip/hip_runtime.h>

#define NAGENTS 32
#define NOBSV   2
#define H1D     128
#define HXD     64
#define NACTD   5

typedef _Float16 h8 __attribute__((ext_vector_type(8)));
typedef float f32x4 __attribute__((ext_vector_type(4)));

// MFMA 16x16x32 f16 layouts (validated rounds 8-17):
//   A: lane l holds A[l&15][(l>>4)*8 + j]
//   B: lane l holds B[(l>>4)*8 + j][l&15]
//   D: reg r holds D[(l>>4)*4 + r][l&15]
// Symmetry: A-frag image of M^T == B-frag image of M -> wfrag serves both roles.
// ci buffer: [agent][row][128] f16 — cols 0..63 = hidden (K1), 64..127 = comms (K2).
// wfrag: [mat*32 + a][1024] h8 — single-f16 fragment images (1 MB, L2-resident).
// ci stores in K1/K2 go through a wave-private LDS bounce: scalar D-scatter to
// LDS, then contiguous h8 (16B/lane) global stores — replaces 16 scalar 2-B
// global stores per thread with 4 dwordx4 stores.

static __device__ __forceinline__ float fast_tanh(float x) {
    float e = __builtin_amdgcn_exp2f(x * 2.885390081777927f);  // exp(2x)
    return fmaf(-2.0f, __builtin_amdgcn_rcpf(e + 1.0f), 1.0f);
}

// ================= Kernel 0: weight fragment prep (per agent, once) =================
__global__ __launch_bounds__(256, 4) void k0_prep(
    const float* __restrict__ W2, const float* __restrict__ Wc,
    h8* __restrict__ wfrag)
{
    const int a = blockIdx.x;
    const int tid = threadIdx.x;
    #pragma unroll
    for (int mat = 0; mat < 2; ++mat) {
        const float* src = (mat == 0 ? W2 : Wc) + (size_t)a * (H1D * HXD);
        h8* dst = wfrag + (size_t)(mat * NAGENTS + a) * 1024;
        #pragma unroll
        for (int s4 = 0; s4 < 4; ++s4) {
            const int s  = tid + s4 * 256;
            const int fi = s >> 6, ln = s & 63;
            const int k0  = (fi >> 2) * 32 + (ln >> 4) * 8;
            const int col = (fi & 3) * 16 + (ln & 15);
            h8 w;
            #pragma unroll
            for (int j = 0; j < 8; ++j)
                w[j] = (_Float16)src[(size_t)(k0 + j) * HXD + col];
            dst[s] = w;
        }
    }
}

// ============================ Kernel 1: encoder ============================
// grid (NAGENTS, B/128). B-frags staged wfrag->LDS; D stored via LDS bounce.
__global__ __launch_bounds__(256, 4) void k1_encoder(
    const float* __restrict__ obs, const float* __restrict__ W1,
    const float* __restrict__ b1, const float* __restrict__ b2,
    _Float16* __restrict__ ci, const h8* __restrict__ wfrag, int B)
{
    __shared__ h8       s_wf[16][64];
    __shared__ float    s_w1a[H1D], s_w1b[H1D], s_b1[H1D], s_b2[HXD];
    __shared__ float    s_ob[128][2];
    __shared__ _Float16 s_st[4][32][72];   // wave-private store bounce (18.4 KB)

    const int a   = blockIdx.x;
    const int r0  = blockIdx.y * 128;
    const int tid = threadIdx.x;
    const int wv  = tid >> 6, lane = tid & 63;
    const int l15 = lane & 15, lq = lane >> 4;

    {
        const float* w1p = W1 + a * (NOBSV * H1D);
        if (tid < H1D) {
            s_w1a[tid] = w1p[tid];
            s_w1b[tid] = w1p[H1D + tid];
            s_b1[tid]  = b1[a * H1D + tid];
        } else if (tid < H1D + HXD) {
            s_b2[tid - H1D] = b2[a * HXD + (tid - H1D)];
        }
        if (tid < 128) {
            const float2 ov = *reinterpret_cast<const float2*>(
                obs + ((size_t)(r0 + tid) * NAGENTS + a) * NOBSV);
            s_ob[tid][0] = ov.x; s_ob[tid][1] = ov.y;
        }
        const h8* srcf = wfrag + (size_t)a * 1024;
        h8* dstf = &s_wf[0][0];
        #pragma unroll
        for (int c = 0; c < 4; ++c) dstf[tid + c * 256] = srcf[tid + c * 256];
    }
    __syncthreads();

    const float o0r0 = s_ob[wv * 32 + l15][0],      o1r0 = s_ob[wv * 32 + l15][1];
    const float o0r1 = s_ob[wv * 32 + 16 + l15][0], o1r1 = s_ob[wv * 32 + 16 + l15][1];

    f32x4 acc[2][4];
    #pragma unroll
    for (int m = 0; m < 2; ++m)
        #pragma unroll
        for (int n = 0; n < 4; ++n) {
            const float bv = s_b2[n * 16 + l15];
            acc[m][n] = (f32x4){bv, bv, bv, bv};
        }
    #pragma unroll
    for (int kt = 0; kt < 4; ++kt) {
        h8 af0, af1;
        #pragma unroll
        for (int j = 0; j < 8; ++j) {
            const int k = kt * 32 + lq * 8 + j;
            const float wa = s_w1a[k], wb = s_w1b[k], bb = s_b1[k];
            af0[j] = (_Float16)fmaxf(fmaf(o1r0, wb, fmaf(o0r0, wa, bb)), 0.0f);
            af1[j] = (_Float16)fmaxf(fmaf(o1r1, wb, fmaf(o0r1, wa, bb)), 0.0f);
        }
        #pragma unroll
        for (int n = 0; n < 4; ++n) {
            h8 bh = s_wf[kt * 4 + n][lane];
            acc[0][n] = __builtin_amdgcn_mfma_f32_16x16x32_f16(af0, bh, acc[0][n], 0, 0, 0);
            acc[1][n] = __builtin_amdgcn_mfma_f32_16x16x32_f16(af1, bh, acc[1][n], 0, 0, 0);
        }
    }
    // D-scatter (relu) into wave-private bounce, then vectorized h8 stores
    #pragma unroll
    for (int m = 0; m < 2; ++m)
        #pragma unroll
        for (int r = 0; r < 4; ++r) {
            const int row = m * 16 + lq * 4 + r;   // 0..31 within wave tile
            #pragma unroll
            for (int n = 0; n < 4; ++n)
                s_st[wv][row][n * 16 + l15] = (_Float16)fmaxf(acc[m][n][r], 0.0f);
        }
    asm volatile("s_waitcnt lgkmcnt(0)" ::: "memory");
    __builtin_amdgcn_sched_barrier(0);
    #pragma unroll
    for (int it = 0; it < 4; ++it) {
        const int idx = it * 64 + lane;    // 0..255
        const int row = idx >> 3;          // 0..31
        const int c8  = idx & 7;
        h8 v = *reinterpret_cast<const h8*>(&s_st[wv][row][c8 * 8]);
        *reinterpret_cast<h8*>(
            ci + ((size_t)a * B + (r0 + wv * 32 + row)) * 128 + c8 * 8) = v;
    }
}

// ========================= Kernel 2: mask + comms (MFMA) =========================
// grid (B/8). Wave w owns rows 2w,2w+1. Mask: f32 screen + exact-f64 fallback.
// cms stores via LDS bounce reusing the dead s_tt[rw] slice (wave-private).
__global__ __launch_bounds__(256, 3) void k2_comms(
    const float* __restrict__ obs, _Float16* __restrict__ ci, int B)
{
    __shared__ __align__(16) _Float16 s_tt[8][64][40];  // hidden transposed [o][j]
    __shared__ float s_o[8][66];
    __shared__ float s_Ji[8][32];

    const int r0  = blockIdx.x * 8;
    const int tid = threadIdx.x;
    const int wv  = tid >> 6, lane = tid & 63;
    const int l15 = lane & 15, lq = lane >> 4;

    if (tid < 128) {
        const float4 v = reinterpret_cast<const float4*>(obs + (size_t)r0 * NAGENTS * NOBSV)[tid];
        const int row = tid >> 4, seg = tid & 15;
        *reinterpret_cast<float4*>(&s_o[row][seg * 4]) = v;
    }
    __syncthreads();

    const int row = tid >> 5;   // block-local row; wave wv holds rows 2wv, 2wv+1
    const int u   = tid & 31;

    {   // transposed hidden (ci cols 0..63), agent-major layout
        const h8* src = reinterpret_cast<const h8*>(
            ci + ((size_t)u * B + (r0 + row)) * 128);
        #pragma unroll
        for (int c = 0; c < 8; ++c) {
            h8 v = src[c];
            #pragma unroll
            for (int e = 0; e < 8; ++e) s_tt[row][c * 8 + e][u] = v[e];
        }
    }
    unsigned int bits = 0u;
    {   // mask row: f32 margin screen + exact-f64 fallback (bit-exact verdicts)
        const float xif = s_o[row][u * 2 + 0] * 2.0f;
        const float yif = s_o[row][u * 2 + 1] * 6.0f;
        #pragma unroll 4
        for (int j = 0; j < NAGENTS; ++j) {
            const float xj = s_o[row][j * 2 + 0] * 2.0f;
            const float yj = s_o[row][j * 2 + 1] * 6.0f;
            const float d = fabsf(xif - xj) + fabsf(yif - yj);
            bool in;
            if (__builtin_expect(d > 1e-4f && fabsf(d - 2.0f) > 1e-4f, 1)) {
                in = (d < 2.0f);
            } else {
                const double xi64 = (double)s_o[row][u * 2 + 0] * 2.0;
                const double yi64 = (double)s_o[row][u * 2 + 1] * 6.0;
                const double xj64 = (double)s_o[row][j * 2 + 0] * 2.0;
                const double yj64 = (double)s_o[row][j * 2 + 1] * 6.0;
                const double dd = fabs(xi64 - xj64) + fabs(yi64 - yj64);
                in = (dd > 0.0 && dd < 2.0);
            }
            if (in) bits |= (1u << j);
        }
        s_Ji[row][u] = 1.0f / fmaxf((float)__popc(bits), 1.0f);
    }
    asm volatile("s_waitcnt lgkmcnt(0)" ::: "memory");
    __builtin_amdgcn_sched_barrier(0);

    #pragma unroll
    for (int rr = 0; rr < 2; ++rr) {
        const int rw = wv * 2 + rr;
        const unsigned int ba0 = (unsigned int)__shfl((int)bits, rr * 32 + l15, 64);
        const unsigned int ba1 = (unsigned int)__shfl((int)bits, rr * 32 + 16 + l15, 64);
        h8 a0, a1;
        #pragma unroll
        for (int j = 0; j < 8; ++j) {
            a0[j] = ((ba0 >> (lq * 8 + j)) & 1u) ? (_Float16)1.0f : (_Float16)0.0f;
            a1[j] = ((ba1 >> (lq * 8 + j)) & 1u) ? (_Float16)1.0f : (_Float16)0.0f;
        }
        f32x4 acc[2][4];
        #pragma unroll
        for (int m = 0; m < 2; ++m)
            #pragma unroll
            for (int n = 0; n < 4; ++n) acc[m][n] = (f32x4){0.f, 0.f, 0.f, 0.f};
        #pragma unroll
        for (int n = 0; n < 4; ++n) {
            h8 b = *reinterpret_cast<const h8*>(&s_tt[rw][n * 16 + l15][lq * 8]);
            acc[0][n] = __builtin_amdgcn_mfma_f32_16x16x32_f16(a0, b, acc[0][n], 0, 0, 0);
            acc[1][n] = __builtin_amdgcn_mfma_f32_16x16x32_f16(a1, b, acc[1][n], 0, 0, 0);
        }
        // D-scatter (scaled by 1/J) into the now-dead s_tt[rw] slice (wave-private,
        // reads above already consumed by the MFMAs), then vectorized h8 stores.
        _Float16* bounce = &s_tt[rw][0][0];   // >= 32*72 halves available
        #pragma unroll
        for (int m = 0; m < 2; ++m)
            #pragma unroll
            for (int r = 0; r < 4; ++r) {
                const int ai = m * 16 + lq * 4 + r;
                const float Ji = s_Ji[rw][ai];
                #pragma unroll
                for (int n = 0; n < 4; ++n)
                    bounce[ai * 72 + n * 16 + l15] = (_Float16)(acc[m][n][r] * Ji);
            }
        asm volatile("s_waitcnt lgkmcnt(0)" ::: "memory");
        __builtin_amdgcn_sched_barrier(0);
        #pragma unroll
        for (int it = 0; it < 4; ++it) {
            const int idx = it * 64 + lane;    // 0..255
            const int ai  = idx >> 3;          // agent 0..31
            const int c8  = idx & 7;
            h8 v = *reinterpret_cast<const h8*>(&bounce[ai * 72 + c8 * 8]);
            *reinterpret_cast<h8*>(
                ci + ((size_t)ai * B + (r0 + rw)) * 128 + 64 + c8 * 8) = v;
        }
    }
}

// ==================== Kernel 3: comm MLP + decoder (MFMA, swapped operands) ====================
__global__ __launch_bounds__(256, 4) void k3_head(
    const _Float16* __restrict__ ci, const float* __restrict__ bc,
    const float* __restrict__ Wd, const float* __restrict__ bd,
    float* __restrict__ out, const h8* __restrict__ wfrag, int B)
{
    __shared__ h8    s_wf[16][64];
    __shared__ float s_wd[HXD][9];   // stride 9 -> conflict-free
    __shared__ float s_bc[HXD];
    __shared__ float s_bd[8];

    const int a   = blockIdx.x;
    const int r0  = blockIdx.y * 128;
    const int tid = threadIdx.x;
    const int wv  = tid >> 6, lane = tid & 63;
    const int l15 = lane & 15, lq = lane >> 4;

    {
        const h8* srcf = wfrag + (size_t)(NAGENTS + a) * 1024;
        h8* dstf = &s_wf[0][0];
        #pragma unroll
        for (int c = 0; c < 4; ++c) dstf[tid + c * 256] = srcf[tid + c * 256];
        if (tid < HXD) {
            s_bc[tid] = bc[a * HXD + tid];
            #pragma unroll
            for (int o = 0; o < NACTD; ++o)
                s_wd[tid][o] = Wd[(size_t)a * (HXD * NACTD) + tid * NACTD + o];
        } else if (tid < HXD + NACTD) {
            s_bd[tid - HXD] = bd[a * NACTD + (tid - HXD)];
        }
    }
    __syncthreads();

    // B-fragments: lane l holds ci[row = base + l15][k = kt*32 + lq*8 + j]
    const _Float16* rb0 = ci + ((size_t)a * B + (r0 + wv * 32 + l15)) * 128;
    const _Float16* rb1 = rb0 + (size_t)16 * 128;

    // acc[m][n]: o-tile m (o = m*16 + lq*4 + r), row-tile n (row = wv*32 + n*16 + l15)
    f32x4 acc[4][2];
    #pragma unroll
    for (int m = 0; m < 4; ++m) {
        const float4 bv = *reinterpret_cast<const float4*>(&s_bc[m * 16 + lq * 4]);
        acc[m][0] = (f32x4){bv.x, bv.y, bv.z, bv.w};
        acc[m][1] = (f32x4){bv.x, bv.y, bv.z, bv.w};
    }
    #pragma unroll
    for (int kt = 0; kt < 4; ++kt) {
        h8 bf0 = *reinterpret_cast<const h8*>(rb0 + kt * 32 + lq * 8);
        h8 bf1 = *reinterpret_cast<const h8*>(rb1 + kt * 32 + lq * 8);
        #pragma unroll
        for (int m = 0; m < 4; ++m) {
            h8 ah = s_wf[kt * 4 + m][lane];
            acc[m][0] = __builtin_amdgcn_mfma_f32_16x16x32_f16(ah, bf0, acc[m][0], 0, 0, 0);
            acc[m][1] = __builtin_amdgcn_mfma_f32_16x16x32_f16(ah, bf1, acc[m][1], 0, 0, 0);
        }
    }

    // epilogue: tanh + decoder (lane-local 16 o-dims) + 2-round reduce + store
    #pragma unroll
    for (int n = 0; n < 2; ++n) {
        float qv[NACTD];
        #pragma unroll
        for (int o = 0; o < NACTD; ++o) qv[o] = 0.0f;
        #pragma unroll
        for (int m = 0; m < 4; ++m)
            #pragma unroll
            for (int r = 0; r < 4; ++r) {
                const float t = fast_tanh(acc[m][n][r]);
                const float* wd = s_wd[m * 16 + lq * 4 + r];
                #pragma unroll
                for (int o = 0; o < NACTD; ++o) qv[o] = fmaf(t, wd[o], qv[o]);
            }
        #pragma unroll
        for (int o = 0; o < NACTD; ++o) {
            qv[o] += __shfl_xor(qv[o], 16, 64);
            qv[o] += __shfl_xor(qv[o], 32, 64);
        }
        if (lq == 0) {
            const int row = wv * 32 + n * 16 + l15;
            float* op = out + ((size_t)(r0 + row) * NAGENTS + a) * NACTD;
            #pragma unroll
            for (int o = 0; o < NACTD; ++o) op[o] = qv[o] + s_bd[o];
        }
    }
}

// ================= Fallback: round-6 fused kernel (passed @991us) =================
#define TBATCH  8
#define NWAVES  4
#define BFST    2056
#define HROWST  132
__global__ __launch_bounds__(256, 3) void qnet_fused_fb(
    const float* __restrict__ obs,
    const float* __restrict__ W1, const float* __restrict__ b1,
    const float* __restrict__ W2, const float* __restrict__ b2,
    const float* __restrict__ Wc, const float* __restrict__ bc,
    const float* __restrict__ Wd, const float* __restrict__ bd,
    float* __restrict__ out)
{
    __shared__ float    s_obs[TBATCH][NAGENTS * 2 + 2];
    __shared__ _Float16 s_hid[TBATCH * BFST];
    __shared__ float    s_h[NWAVES][TBATCH][HROWST];

    const int tid  = threadIdx.x;
    const int wave = tid >> 6;
    const int lane = tid & 63;
    const int lb   = lane & 7;
    const int og   = lane >> 3;
    const int b0   = blockIdx.x * TBATCH;

    {
        const float2* src = reinterpret_cast<const float2*>(obs + (size_t)b0 * (NAGENTS * NOBSV));
        float2 v = src[tid];
        s_obs[tid >> 5][(tid & 31) * 2 + 0] = v.x;
        s_obs[tid >> 5][(tid & 31) * 2 + 1] = v.y;
    }
    __syncthreads();

    const int p_a = tid >> 3;
    const int p_b = tid & 7;
    unsigned int bits = 0u;
    float Jf;
    {
        const double xi = (double)s_obs[p_b][p_a * 2 + 0] * 2.0;
        const double yi = (double)s_obs[p_b][p_a * 2 + 1] * 6.0;
        #pragma unroll
        for (int j = 0; j < NAGENTS; ++j) {
            double xj = (double)s_obs[p_b][j * 2 + 0] * 2.0;
            double yj = (double)s_obs[p_b][j * 2 + 1] * 6.0;
            double d = fabs(xi - xj) + fabs(yi - yj);
            if (d > 0.0 && d < 2.0) bits |= (1u << j);
        }
        Jf = fmaxf((float)__popc(bits), 1.0f);
    }

    #pragma unroll 1
    for (int ai = 0; ai < 8; ++ai) {
        const int a = wave * 8 + ai;
        const float o0 = s_obs[lb][a * 2 + 0];
        const float o1 = s_obs[lb][a * 2 + 1];
        {
            const float* __restrict__ w1a = W1 + a * (NOBSV * H1D) + og * 16;
            const float* __restrict__ w1b = w1a + H1D;
            const float* __restrict__ b1p = b1 + a * H1D + og * 16;
            float* hdst = &s_h[wave][lb][og * 16];
            #pragma unroll
            for (int c = 0; c < 4; ++c) {
                float4 wa = *reinterpret_cast<const float4*>(w1a + 4 * c);
                float4 wb = *reinterpret_cast<const float4*>(w1b + 4 * c);
                float4 bv = *reinterpret_cast<const float4*>(b1p + 4 * c);
                float4 hv;
                hv.x = fmaxf(fmaf(o1, wb.x, fmaf(o0, wa.x, bv.x)), 0.0f);
                hv.y = fmaxf(fmaf(o1, wb.y, fmaf(o0, wa.y, bv.y)), 0.0f);
                hv.z = fmaxf(fmaf(o1, wb.z, fmaf(o0, wa.z, bv.z)), 0.0f);
                hv.w = fmaxf(fmaf(o1, wb.w, fmaf(o0, wa.w, bv.w)), 0.0f);
                *reinterpret_cast<float4*>(hdst + 4 * c) = hv;
            }
        }
        asm volatile("s_waitcnt lgkmcnt(0)" ::: "memory");
        __builtin_amdgcn_sched_barrier(0);

        const float* __restrict__ w2p = W2 + a * (H1D * HXD) + og * 8;
        const float* __restrict__ b2p = b2 + a * HXD + og * 8;
        float acc[8];
        {
            float4 bv0 = *reinterpret_cast<const float4*>(b2p + 0);
            float4 bv1 = *reinterpret_cast<const float4*>(b2p + 4);
            acc[0] = bv0.x; acc[1] = bv0.y; acc[2] = bv0.z; acc[3] = bv0.w;
            acc[4] = bv1.x; acc[5] = bv1.y; acc[6] = bv1.z; acc[7] = bv1.w;
        }
        const float* hsrc = &s_h[wave][lb][0];
        #pragma unroll 8
        for (int k = 0; k < H1D; ++k) {
            const float hv = hsrc[k];
            const float* wr = w2p + k * HXD;
            float4 wv0 = *reinterpret_cast<const float4*>(wr + 0);
            float4 wv1 = *reinterpret_cast<const float4*>(wr + 4);
            acc[0] = fmaf(hv, wv0.x, acc[0]);
            acc[1] = fmaf(hv, wv0.y, acc[1]);
            acc[2] = fmaf(hv, wv0.z, acc[2]);
            acc[3] = fmaf(hv, wv0.w, acc[3]);
            acc[4] = fmaf(hv, wv1.x, acc[4]);
            acc[5] = fmaf(hv, wv1.y, acc[5]);
            acc[6] = fmaf(hv, wv1.z, acc[6]);
            acc[7] = fmaf(hv, wv1.w, acc[7]);
        }
        h8 hh;
        #pragma unroll
        for (int i = 0; i < 8; ++i) hh[i] = (_Float16)fmaxf(acc[i], 0.0f);
        *reinterpret_cast<h8*>(&s_hid[lb * BFST + a * HXD + og * 8]) = hh;
    }
    __syncthreads();

    #pragma unroll 1
    for (int ai = 0; ai < 8; ++ai) {
        const int a = wave * 8 + ai;
        const int srcm = ai * 8 + lb;
        const unsigned int mbits = (unsigned int)__shfl((int)bits, srcm, 64);
        const float Jv = __shfl(Jf, srcm, 64);

        float cm8[8];
        #pragma unroll
        for (int i = 0; i < 8; ++i) cm8[i] = 0.0f;
        {
            const _Float16* hrow = &s_hid[lb * BFST + og * 8];
            #pragma unroll 8
            for (int j = 0; j < NAGENTS; ++j) {
                const float m = (float)((mbits >> j) & 1u);
                h8 v = *reinterpret_cast<const h8*>(hrow + j * HXD);
                cm8[0] = fmaf(m, (float)v[0], cm8[0]);
                cm8[1] = fmaf(m, (float)v[1], cm8[1]);
                cm8[2] = fmaf(m, (float)v[2], cm8[2]);
                cm8[3] = fmaf(m, (float)v[3], cm8[3]);
                cm8[4] = fmaf(m, (float)v[4], cm8[4]);
                cm8[5] = fmaf(m, (float)v[5], cm8[5]);
                cm8[6] = fmaf(m, (float)v[6], cm8[6]);
                cm8[7] = fmaf(m, (float)v[7], cm8[7]);
            }
        }
        {
            float* cw = &s_h[wave][lb][og * 8];
            *reinterpret_cast<float4*>(cw + 0) =
                make_float4(cm8[0]/Jv, cm8[1]/Jv, cm8[2]/Jv, cm8[3]/Jv);
            *reinterpret_cast<float4*>(cw + 4) =
                make_float4(cm8[4]/Jv, cm8[5]/Jv, cm8[6]/Jv, cm8[7]/Jv);
        }
        asm volatile("s_waitcnt lgkmcnt(0)" ::: "memory");
        __builtin_amdgcn_sched_barrier(0);

        const float* __restrict__ wcp = Wc + a * (2 * HXD * HXD) + og * 8;
        const float* __restrict__ bcp = bc + a * HXD + og * 8;
        float acc[8];
        {
            float4 bv0 = *reinterpret_cast<const float4*>(bcp + 0);
            float4 bv1 = *reinterpret_cast<const float4*>(bcp + 4);
            acc[0] = bv0.x; acc[1] = bv0.y; acc[2] = bv0.z; acc[3] = bv0.w;
            acc[4] = bv1.x; acc[5] = bv1.y; acc[6] = bv1.z; acc[7] = bv1.w;
        }
        const _Float16* hbase = &s_hid[lb * BFST + a * HXD];
        #pragma unroll 8
        for (int k = 0; k < HXD; ++k) {
            const float ci2 = (float)hbase[k];
            const float* wr = wcp + k * HXD;
            float4 wv0 = *reinterpret_cast<const float4*>(wr + 0);
            float4 wv1 = *reinterpret_cast<const float4*>(wr + 4);
            acc[0] = fmaf(ci2, wv0.x, acc[0]);
            acc[1] = fmaf(ci2, wv0.y, acc[1]);
            acc[2] = fmaf(ci2, wv0.z, acc[2]);
            acc[3] = fmaf(ci2, wv0.w, acc[3]);
            acc[4] = fmaf(ci2, wv1.x, acc[4]);
            acc[5] = fmaf(ci2, wv1.y, acc[5]);
            acc[6] = fmaf(ci2, wv1.z, acc[6]);
            acc[7] = fmaf(ci2, wv1.w, acc[7]);
        }
        #pragma unroll 8
        for (int k2 = 0; k2 < HXD; ++k2) {
            const float ci2 = s_h[wave][lb][k2];
            const float* wr = wcp + (HXD + k2) * HXD;
            float4 wv0 = *reinterpret_cast<const float4*>(wr + 0);
            float4 wv1 = *reinterpret_cast<const float4*>(wr + 4);
            acc[0] = fmaf(ci2, wv0.x, acc[0]);
            acc[1] = fmaf(ci2, wv0.y, acc[1]);
            acc[2] = fmaf(ci2, wv0.z, acc[2]);
            acc[3] = fmaf(ci2, wv0.w, acc[3]);
            acc[4] = fmaf(ci2, wv1.x, acc[4]);
            acc[5] = fmaf(ci2, wv1.y, acc[5]);
            acc[6] = fmaf(ci2, wv1.z, acc[6]);
            acc[7] = fmaf(ci2, wv1.w, acc[7]);
        }
        float qv[NACTD];
        #pragma unroll
        for (int o = 0; o < NACTD; ++o) qv[o] = 0.0f;
        const float* __restrict__ wdp = Wd + a * (HXD * NACTD) + og * 8 * NACTD;
        #pragma unroll
        for (int i = 0; i < 8; ++i) {
            float h2 = tanhf(acc[i]);
            #pragma unroll
            for (int o = 0; o < NACTD; ++o)
                qv[o] = fmaf(h2, wdp[i * NACTD + o], qv[o]);
        }
        #pragma unroll
        for (int o = 0; o < NACTD; ++o) {
            qv[o] += __shfl_xor(qv[o], 8, 64);
            qv[o] += __shfl_xor(qv[o], 16, 64);
            qv[o] += __shfl_xor(qv[o], 32, 64);
        }
        if (og == 0) {
            float* op = out + ((size_t)(b0 + lb) * NAGENTS + a) * NACTD;
            const float* bdp = bd + a * NACTD;
            #pragma unroll
            for (int o = 0; o < NACTD; ++o) op[o] = qv[o] + bdp[o];
        }
    }
}

extern "C" void kernel_launch(void* const* d_in, const int* in_sizes, int n_in,
                              void* d_out, int out_size, void* d_ws, size_t ws_size,
                              hipStream_t stream) {
    (void)out_size;
    if (n_in < 9) return;
    const float* obs = (const float*)d_in[0];
    const float* W1  = (const float*)d_in[1];
    const float* b1v = (const float*)d_in[2];
    const float* W2  = (const float*)d_in[3];
    const float* b2v = (const float*)d_in[4];
    const float* Wc  = (const float*)d_in[5];
    const float* bcv = (const float*)d_in[6];
    const float* Wd  = (const float*)d_in[7];
    const float* bdv = (const float*)d_in[8];
    float* out = (float*)d_out;
    const int Btot = in_sizes[0] / (NAGENTS * NOBSV);  // 16384

    const size_t ciBytes   = (size_t)Btot * NAGENTS * 128 * 2;  // 134 MB
    const size_t fragBytes = (size_t)2 * NAGENTS * 1024 * 16;   // 1 MB
    dim3 blk(256);
    if (ws_size >= ciBytes + fragBytes && (Btot % 128) == 0) {
        _Float16* ci = (_Float16*)d_ws;
        h8* wfrag = (h8*)((char*)d_ws + ciBytes);
        k0_prep<<<dim3(NAGENTS), blk, 0, stream>>>(W2, Wc, wfrag);
        k1_encoder<<<dim3(NAGENTS, Btot / 128), blk, 0, stream>>>(
            obs, W1, b1v, b2v, ci, wfrag, Btot);
        k2_comms<<<dim3(Btot / 8), blk, 0, stream>>>(obs, ci, Btot);
        k3_head<<<dim3(NAGENTS, Btot / 128), blk, 0, stream>>>(
            ci, bcv, Wd, bdv, out, wfrag, Btot);
    } else {
        qnet_fused_fb<<<dim3(Btot / TBATCH), dim3(256), 0, stream>>>(
            obs, W1, b1v, W2, b2v, Wc, bcv, Wd, bdv, out);
    }
}